// Round 13
// baseline (180.085 us; speedup 1.0000x reference)
//
#include <hip/hip_runtime.h>
#include <cstdint>
#include <cstddef>

#define B_ 16384
#define K_ 512
#define H_ 4096
#define O_ 512

typedef __attribute__((ext_vector_type(4))) float f32x4;
typedef __attribute__((ext_vector_type(8))) short bf16x8;

#define EPS_FLAG 0.125f

// ---------------------------------------------------------------------------
// Exact helpers (bitwise vs numpy reference — proven in rounds 1-12)
// ---------------------------------------------------------------------------
__device__ inline unsigned short f32_to_bf16_rne(float f) {
  unsigned u = __float_as_uint(f);
  unsigned r = (u + 0x7fffu + ((u >> 16) & 1u)) >> 16;
  return (unsigned short)r;
}

__device__ float np_pairwise_sumsq512(const float* __restrict__ a) {
  float s[4];
  #pragma unroll
  for (int blk = 0; blk < 4; ++blk) {
    const float* p = a + blk * 128;
    float r[8];
    #pragma unroll
    for (int j = 0; j < 8; ++j) r[j] = __fmul_rn(p[j], p[j]);
    for (int i = 8; i < 128; i += 8) {
      #pragma unroll
      for (int j = 0; j < 8; ++j) r[j] = __fadd_rn(r[j], __fmul_rn(p[i + j], p[i + j]));
    }
    s[blk] = __fadd_rn(__fadd_rn(__fadd_rn(r[0], r[1]), __fadd_rn(r[2], r[3])),
                       __fadd_rn(__fadd_rn(r[4], r[5]), __fadd_rn(r[6], r[7])));
  }
  return __fadd_rn(__fadd_rn(s[0], s[1]), __fadd_rn(s[2], s[3]));
}

__global__ __launch_bounds__(256) void prep_rows_kernel(
    const float* __restrict__ src, unsigned short* __restrict__ hi,
    float* __restrict__ sumsq, int nrows) {
  __shared__ float buf[8 * 512];
  const int r0 = blockIdx.x * 8;
  const int tid = (int)threadIdx.x;

  #pragma unroll
  for (int it = 0; it < 4; ++it) {
    int i = tid + it * 256;
    float4 v = ((const float4*)(src + (size_t)r0 * K_))[i];
    ((float4*)buf)[i] = v;
    ushort4 h;
    h.x = f32_to_bf16_rne(v.x);
    h.y = f32_to_bf16_rne(v.y);
    h.z = f32_to_bf16_rne(v.z);
    h.w = f32_to_bf16_rne(v.w);
    ((ushort4*)(hi + (size_t)r0 * K_))[i] = h;
  }
  __syncthreads();

  const int row = tid >> 5, l = tid & 31, blk = l >> 3, j = l & 7;
  const float* p = buf + row * 512 + blk * 128;
  float r = __fmul_rn(p[j], p[j]);
  #pragma unroll
  for (int i = 8; i < 128; i += 8) r = __fadd_rn(r, __fmul_rn(p[i + j], p[i + j]));
  r = __fadd_rn(r, __shfl_xor(r, 1));
  r = __fadd_rn(r, __shfl_xor(r, 2));
  r = __fadd_rn(r, __shfl_xor(r, 4));
  r = __fadd_rn(r, __shfl_xor(r, 8));
  r = __fadd_rn(r, __shfl_xor(r, 16));
  if (l == 0 && r0 + row < nrows) sumsq[r0 + row] = r;
}

__global__ void rowsumsq_kernel(const float* __restrict__ src, float* __restrict__ dst,
                                int nrows) {
  int r = blockIdx.x * blockDim.x + threadIdx.x;
  if (r < nrows) dst[r] = np_pairwise_sumsq512(src + (size_t)r * K_);
}

// G [O_][H_] -> GT [H_][O_]
__global__ void transposeG_kernel(const float* __restrict__ G, float* __restrict__ GT) {
  __shared__ float t[32][33];
  int h0 = blockIdx.x * 32, o0 = blockIdx.y * 32;
  for (int i = threadIdx.y; i < 32; i += 8)
    t[i][threadIdx.x] = G[(size_t)(o0 + i) * H_ + h0 + threadIdx.x];
  __syncthreads();
  for (int i = threadIdx.y; i < 32; i += 8)
    GT[(size_t)(h0 + i) * O_ + o0 + threadIdx.x] = t[threadIdx.x][i];
}

// ---------------------------------------------------------------------------
// Phase 1: 256x256 tile, 8 waves (2Mx4N), BK=64, 8-phase-style schedule:
// per K-tile 4 phases {12 ds_read frags | 2-3 prefetch gl_lds -> s_barrier ->
// lgkmcnt(0) -> setprio(1) 16 MFMA setprio(0) -> s_barrier}; prefetch of
// kt+1 spread over kt's phases 0-2; one __syncthreads drain per K-tile.
// LDS: 4 half-slots x 32KB (A[128][64] + B[128][64] per slot), ring of 2
// K-tiles; intra-kt raw barriers are pure schedulers (slots read-only).
// T2 XOR-8 swizzle (proven R12): source-swizzled gl_lds, swizzled ds_read.
// ---------------------------------------------------------------------------
__device__ inline void stage_chunk(char* lds_panel, const unsigned short* __restrict__ src,
                                   int rowbase, int kt, int chunk, int lane) {
  int u = chunk * 64 + lane;            // 16B unit within [128][64]bf16 panel
  int row = u >> 3, slot = u & 7;
  const char* g = (const char*)src + (size_t)(rowbase + row) * (K_ * 2) + kt * 128 +
                  ((slot ^ (row & 7)) * 16);
  __builtin_amdgcn_global_load_lds((const __attribute__((address_space(1))) void*)g,
                                   (__attribute__((address_space(3))) void*)(lds_panel + chunk * 1024),
                                   16, 0, 0);
}

__global__ __launch_bounds__(512, 2) void phase1_mfma_kernel(
    const unsigned short* __restrict__ xhi, const unsigned short* __restrict__ whi,
    const float* __restrict__ wsq, const float* __restrict__ xsq,
    float* __restrict__ gmin16 /*[B_][256]*/,
    unsigned short* __restrict__ mk16 /*[B_][256]*/) {
  // ring: 4 slots x 32KB (A panel at +0, B panel at +16384) = 128KB
  // epilogue union: T 8 x [16][129] f32 (66048B), EpiF [256][16] f32 @66048,
  //                 EpiM [256][16] u16 @82432
  __shared__ __align__(16) char smem[131072];
  const int tid = (int)threadIdx.x;
  const int wid = tid >> 6, lane = tid & 63;
  const int wr = wid >> 2, wc = wid & 3;     // 2M x 4N waves; per-wave 128x64
  const int cb = blockIdx.y;
  const int row0 = blockIdx.x * 256, col0 = cb * 256;

  f32x4 acc[8][4];
  #pragma unroll
  for (int i = 0; i < 8; ++i)
    #pragma unroll
    for (int j = 0; j < 4; ++j) acc[i][j] = (f32x4){0.f, 0.f, 0.f, 0.f};

  const int r16 = lane & 15, r7 = lane & 7, sg = lane >> 4;
  int offK[2];
  offK[0] = ((sg ^ r7) & 7) * 16;
  offK[1] = (((4 + sg) ^ r7) & 7) * 16;

  // prologue: stage K-tile 0 (both halves) into slots 0,1
  #pragma unroll
  for (int j = 0; j < 2; ++j) {
    stage_chunk(smem, xhi, row0, 0, wid + 8 * j, lane);
    stage_chunk(smem + 16384, whi, col0, 0, wid + 8 * j, lane);
    stage_chunk(smem + 32768, xhi, row0 + 128, 0, wid + 8 * j, lane);
    stage_chunk(smem + 32768 + 16384, whi, col0 + 128, 0, wid + 8 * j, lane);
  }
  __syncthreads();

  for (int kt = 0; kt < 8; ++kt) {
    const char* Apan = smem + ((kt & 1) * 2 + wr) * 32768;
    const char* Bpan = smem + ((kt & 1) * 2 + (wc >> 1)) * 32768 + 16384;
    char* n0 = smem + (((kt + 1) & 1) * 2) * 32768;       // kt+1 half0 slot
    char* n1 = smem + (((kt + 1) & 1) * 2 + 1) * 32768;   // kt+1 half1 slot
    const int brow0 = (wc & 1) * 64;

    #pragma unroll
    for (int q = 0; q < 4; ++q) {
      const int qm = q >> 1, qn = q & 1;
      bf16x8 ah[4][2], bh[2][2];
      #pragma unroll
      for (int mf2 = 0; mf2 < 4; ++mf2)
        #pragma unroll
        for (int ks = 0; ks < 2; ++ks)
          ah[mf2][ks] = *(const bf16x8*)(Apan + (qm * 64 + mf2 * 16 + r16) * 128 + offK[ks]);
      #pragma unroll
      for (int nf2 = 0; nf2 < 2; ++nf2)
        #pragma unroll
        for (int ks = 0; ks < 2; ++ks)
          bh[nf2][ks] = *(const bf16x8*)(Bpan + (brow0 + qn * 32 + nf2 * 16 + r16) * 128 + offK[ks]);

      // prefetch kt+1: 3/3/2/0 loads across phases 0-2
      if (kt < 7) {
        if (q == 0) {
          stage_chunk(n0, xhi, row0, kt + 1, wid, lane);
          stage_chunk(n0, xhi, row0, kt + 1, wid + 8, lane);
          stage_chunk(n0 + 16384, whi, col0, kt + 1, wid, lane);
        } else if (q == 1) {
          stage_chunk(n0 + 16384, whi, col0, kt + 1, wid + 8, lane);
          stage_chunk(n1, xhi, row0 + 128, kt + 1, wid, lane);
          stage_chunk(n1, xhi, row0 + 128, kt + 1, wid + 8, lane);
        } else if (q == 2) {
          stage_chunk(n1 + 16384, whi, col0 + 128, kt + 1, wid, lane);
          stage_chunk(n1 + 16384, whi, col0 + 128, kt + 1, wid + 8, lane);
        }
      }
      __builtin_amdgcn_sched_barrier(0);
      __builtin_amdgcn_s_barrier();
      asm volatile("s_waitcnt lgkmcnt(0)" ::: "memory");
      __builtin_amdgcn_sched_barrier(0);
      __builtin_amdgcn_s_setprio(1);
      #pragma unroll
      for (int ks = 0; ks < 2; ++ks)
        #pragma unroll
        for (int nf2 = 0; nf2 < 2; ++nf2)
          #pragma unroll
          for (int mf2 = 0; mf2 < 4; ++mf2)
            acc[qm * 4 + mf2][qn * 2 + nf2] = __builtin_amdgcn_mfma_f32_16x16x32_bf16(
                ah[mf2][ks], bh[nf2][ks], acc[qm * 4 + mf2][qn * 2 + nf2], 0, 0, 0);
      __builtin_amdgcn_s_setprio(0);
      __builtin_amdgcn_sched_barrier(0);
      __builtin_amdgcn_s_barrier();
    }
    __syncthreads();   // drain: kt+1 staged & visible; slots handed off
  }

  // ---- epilogue ----
  // D layout: col=lane&15, row=(lane>>4)*4+reg. Per wave: 128 rows x 64 cols.
  float* T = (float*)smem + wid * (16 * 129);                  // [16][129]
  float* EpiF = (float*)(smem + 66048);                        // [256][16]
  unsigned short* EpiM = (unsigned short*)(smem + 82432);      // [256][16]

  const float xq0 = xsq[row0 + wr * 128 + lane];
  const float xq1 = xsq[row0 + wr * 128 + 64 + lane];
  const int c = r16;

  #pragma unroll
  for (int nf = 0; nf < 4; ++nf) {
    float wq = wsq[col0 + wc * 64 + nf * 16 + c];
    #pragma unroll
    for (int mf = 0; mf < 8; ++mf)
      #pragma unroll
      for (int r = 0; r < 4; ++r)
        T[c * 129 + mf * 16 + sg * 4 + r] = wq - 2.0f * acc[mf][nf][r];
    asm volatile("s_waitcnt lgkmcnt(0)" ::: "memory");
    __builtin_amdgcn_sched_barrier(0);
    // lane owns local rows {lane, lane+64}
    #pragma unroll
    for (int half = 0; half < 2; ++half) {
      int lrow = lane + half * 64;
      float xq = half ? xq1 : xq0;
      float v[16];
      #pragma unroll
      for (int c2 = 0; c2 < 16; ++c2) v[c2] = T[c2 * 129 + lrow];
      float mn = v[0];
      #pragma unroll
      for (int c2 = 1; c2 < 16; ++c2) mn = fminf(mn, v[c2]);
      unsigned msk = 0;
      #pragma unroll
      for (int c2 = 0; c2 < 16; ++c2)
        if ((v[c2] <= mn + EPS_FLAG) || (v[c2] + xq <= EPS_FLAG)) msk |= 1u << c2;
      EpiF[(wr * 128 + lrow) * 16 + wc * 4 + nf] = mn;
      EpiM[(wr * 128 + lrow) * 16 + wc * 4 + nf] = (unsigned short)msk;
    }
  }
  __syncthreads();

  // cooperative coalesced store: 256 rows x (16 f32 + 16 u16)
  {
    int row = tid >> 1, hf = tid & 1;
    const float* fr = EpiF + row * 16 + hf * 8;
    size_t gbase = (size_t)(row0 + row) * 256 + cb * 16 + hf * 8;
    *(float4*)&gmin16[gbase] = *(const float4*)fr;
    *(float4*)&gmin16[gbase + 4] = *(const float4*)(fr + 4);
    uint4 mv = *(const uint4*)(EpiM + row * 16 + hf * 8);
    *(uint4*)&mk16[gbase] = mv;
  }
}

// ---------------------------------------------------------------------------
// Phase 2: one wave per row. Compact candidate cols (ballot-prefix -> LDS
// list), each lane runs one exact chain (bitwise ascending-k FMA, float4
// loads), wave-reduce (dist_bits,h) key, fused GT gather + index write.
// ---------------------------------------------------------------------------
#define CAND_CAP 512

__global__ __launch_bounds__(256) void phase2_wave_kernel(
    const float* __restrict__ gm /*[B_][256]*/,
    const unsigned short* __restrict__ mk /*[B_][256]*/,
    const float* __restrict__ x, const float* __restrict__ W,
    const float* __restrict__ xsq, const float* __restrict__ wsq,
    const float* __restrict__ GT, float* __restrict__ out) {
  __shared__ float xs[4][512];
  __shared__ unsigned short clist[4][CAND_CAP];
  const int tid = (int)threadIdx.x;
  const int w = tid >> 6, lane = tid & 63;
  const int b = blockIdx.x * 4 + w;

  const float4* xsrc = (const float4*)(x + (size_t)b * K_);
  ((float4*)xs[w])[lane] = xsrc[lane];
  ((float4*)xs[w])[lane + 64] = xsrc[lane + 64];

  float4 v4 = ((const float4*)(gm + (size_t)b * 256))[lane];
  ushort4 m4 = ((const ushort4*)(mk + (size_t)b * 256))[lane];
  float vq[4] = {v4.x, v4.y, v4.z, v4.w};
  unsigned short ms[4] = {m4.x, m4.y, m4.z, m4.w};
  float m = fminf(fminf(vq[0], vq[1]), fminf(vq[2], vq[3]));
  #pragma unroll
  for (int off = 1; off < 64; off <<= 1) m = fminf(m, __shfl_xor(m, off));
  const float xq = xsq[b];
  const float thr = m + EPS_FLAG;

  unsigned cm[4];
  int cnt = 0;
  #pragma unroll
  for (int q = 0; q < 4; ++q) {
    bool flag = (vq[q] <= thr) || (vq[q] + xq <= EPS_FLAG);
    cm[q] = flag ? (unsigned)ms[q] : 0u;
    cnt += __popc(cm[q]);
  }
  int incl = cnt;
  #pragma unroll
  for (int off = 1; off < 64; off <<= 1) {
    int o = __shfl_up(incl, off);
    if (lane >= off) incl += o;
  }
  int offset = incl - cnt;
  int total = __shfl(incl, 63);

  int pos = offset;
  #pragma unroll
  for (int q = 0; q < 4; ++q) {
    unsigned mm = cm[q];
    while (mm) {
      int bit = __ffs(mm) - 1;
      mm &= mm - 1;
      if (pos < CAND_CAP)
        clist[w][pos] = (unsigned short)((4 * lane + q) * 16 + bit);
      ++pos;
    }
  }
  __syncthreads();

  unsigned long long best = 0xFFFFFFFFFFFFFFFFULL;
  if (total <= CAND_CAP) {
    for (int i = lane; i < total; i += 64) {
      int col = (int)clist[w][i];
      const float4* wrow = (const float4*)(W + (size_t)col * K_);
      float acc = 0.0f;
      #pragma unroll 8
      for (int kq = 0; kq < K_ / 4; ++kq) {
        float4 xv = ((const float4*)xs[w])[kq];
        float4 wv = wrow[kq];
        acc = fmaf(xv.x, wv.x, acc);
        acc = fmaf(xv.y, wv.y, acc);
        acc = fmaf(xv.z, wv.z, acc);
        acc = fmaf(xv.w, wv.w, acc);
      }
      float t2 = xq - 2.0f * acc;
      float sq = t2 + wsq[col];
      float d = sqrtf(fmaxf(sq, 0.0f));
      unsigned long long key =
          ((unsigned long long)__float_as_uint(d) << 32) | (unsigned)col;
      best = key < best ? key : best;
    }
  } else {
    for (int c = lane; c < H_; c += 64) {
      int g = c >> 4;
      float gv = gm[(size_t)b * 256 + g];
      if ((gv <= thr || gv + xq <= EPS_FLAG) &&
          ((mk[(size_t)b * 256 + g] >> (c & 15)) & 1)) {
        const float4* wrow = (const float4*)(W + (size_t)c * K_);
        float acc = 0.0f;
        #pragma unroll 8
        for (int kq = 0; kq < K_ / 4; ++kq) {
          float4 xv = ((const float4*)xs[w])[kq];
          float4 wv = wrow[kq];
          acc = fmaf(xv.x, wv.x, acc);
          acc = fmaf(xv.y, wv.y, acc);
          acc = fmaf(xv.z, wv.z, acc);
          acc = fmaf(xv.w, wv.w, acc);
        }
        float t2 = xq - 2.0f * acc;
        float sq = t2 + wsq[c];
        float d = sqrtf(fmaxf(sq, 0.0f));
        unsigned long long key =
            ((unsigned long long)__float_as_uint(d) << 32) | (unsigned)c;
        best = key < best ? key : best;
      }
    }
  }
  #pragma unroll
  for (int off = 1; off < 64; off <<= 1) {
    unsigned long long o = __shfl_xor(best, off);
    best = best < o ? best : o;
  }
  const unsigned h = (unsigned)(best & 0xFFFFFFFFULL);

  const float4* gsrc = (const float4*)(GT + (size_t)h * O_);
  float4* gdst = (float4*)(out + (size_t)b * O_);
  gdst[lane] = gsrc[lane];
  gdst[lane + 64] = gsrc[lane + 64];
  if (lane == 0) out[(size_t)B_ * O_ + b] = (float)h;
}

// ---------------------------------------------------------------------------
// Round-1 fallback (exact f32 vector GEMM + argmin) — used only if ws too small
// ---------------------------------------------------------------------------
#define BM 128
#define BN 128
#define BKK 16

__global__ void init_keys_kernel(unsigned long long* __restrict__ keys) {
  int i = blockIdx.x * blockDim.x + threadIdx.x;
  if (i < B_) keys[i] = 0xFFFFFFFFFFFFFFFFULL;
}

__global__ __launch_bounds__(256) void dist_argmin_kernel(
    const float* __restrict__ x, const float* __restrict__ W,
    const float* __restrict__ xsq, const float* __restrict__ wsq,
    unsigned long long* __restrict__ keys) {
  __shared__ float xs[BKK][BM + 4];
  __shared__ float wsh[BKK][BN + 4];
  const int row0 = blockIdx.x * BM;
  const int col0 = blockIdx.y * BN;
  const int tid = (int)threadIdx.x;
  const int tx = tid & 15, ty = tid >> 4;

  float acc[8][8];
  #pragma unroll
  for (int i = 0; i < 8; ++i)
    #pragma unroll
    for (int j = 0; j < 8; ++j) acc[i][j] = 0.0f;

  for (int kt = 0; kt < K_; kt += BKK) {
    #pragma unroll
    for (int l = 0; l < 2; ++l) {
      int e = tid + l * 256;
      int r = e >> 2, kq = e & 3;
      float4 v = *(const float4*)(x + (size_t)(row0 + r) * K_ + kt + kq * 4);
      xs[kq * 4 + 0][r] = v.x;
      xs[kq * 4 + 1][r] = v.y;
      xs[kq * 4 + 2][r] = v.z;
      xs[kq * 4 + 3][r] = v.w;
      float4 u = *(const float4*)(W + (size_t)(col0 + r) * K_ + kt + kq * 4);
      wsh[kq * 4 + 0][r] = u.x;
      wsh[kq * 4 + 1][r] = u.y;
      wsh[kq * 4 + 2][r] = u.z;
      wsh[kq * 4 + 3][r] = u.w;
    }
    __syncthreads();
    #pragma unroll
    for (int k = 0; k < BKK; ++k) {
      float4 a0 = *(const float4*)&xs[k][ty * 4];
      float4 a1 = *(const float4*)&xs[k][ty * 4 + 64];
      float4 b0 = *(const float4*)&wsh[k][tx * 4];
      float4 b1 = *(const float4*)&wsh[k][tx * 4 + 64];
      float ar[8] = {a0.x, a0.y, a0.z, a0.w, a1.x, a1.y, a1.z, a1.w};
      float br[8] = {b0.x, b0.y, b0.z, b0.w, b1.x, b1.y, b1.z, b1.w};
      #pragma unroll
      for (int i = 0; i < 8; ++i)
        #pragma unroll
        for (int j = 0; j < 8; ++j)
          acc[i][j] = fmaf(ar[i], br[j], acc[i][j]);
    }
    __syncthreads();
  }

  float xv[8], wv[8];
  int rowidx[8], colidx[8];
  #pragma unroll
  for (int i = 0; i < 8; ++i) {
    rowidx[i] = row0 + ty * 4 + (i & 3) + (i >> 2) * 64;
    xv[i] = xsq[rowidx[i]];
  }
  #pragma unroll
  for (int j = 0; j < 8; ++j) {
    colidx[j] = col0 + tx * 4 + (j & 3) + (j >> 2) * 64;
    wv[j] = wsq[colidx[j]];
  }
  #pragma unroll
  for (int i = 0; i < 8; ++i) {
    unsigned long long best = 0xFFFFFFFFFFFFFFFFULL;
    #pragma unroll
    for (int j = 0; j < 8; ++j) {
      float t2 = xv[i] - 2.0f * acc[i][j];
      float sq = t2 + wv[j];
      float d = sqrtf(fmaxf(sq, 0.0f));
      unsigned long long key =
          ((unsigned long long)__float_as_uint(d) << 32) | (unsigned)colidx[j];
      best = key < best ? key : best;
    }
    #pragma unroll
    for (int off = 1; off < 16; off <<= 1) {
      unsigned long long o = __shfl_xor(best, off, 16);
      best = o < best ? o : best;
    }
    if (tx == 0) atomicMin(&keys[rowidx[i]], best);
  }
}

__global__ void finalize_kernel(const unsigned long long* __restrict__ keys,
                                const float* __restrict__ GT,
                                const float* __restrict__ G,
                                float* __restrict__ out, int useGT) {
  int b = blockIdx.x;
  unsigned h = (unsigned)(keys[b] & 0xFFFFFFFFULL);
  if (threadIdx.x == 0) out[(size_t)B_ * O_ + b] = (float)h;
  if (useGT) {
    const float4* src = (const float4*)(GT + (size_t)h * O_);
    float4* dst = (float4*)(out + (size_t)b * O_);
    for (int i = threadIdx.x; i < O_ / 4; i += blockDim.x) dst[i] = src[i];
  } else {
    for (int o = threadIdx.x; o < O_; o += blockDim.x)
      out[(size_t)b * O_ + o] = G[(size_t)o * H_ + h];
  }
}

// ---------------------------------------------------------------------------
extern "C" void kernel_launch(void* const* d_in, const int* in_sizes, int n_in,
                              void* d_out, int out_size, void* d_ws, size_t ws_size,
                              hipStream_t stream) {
  const float* x = (const float*)d_in[0];
  const float* W = (const float*)d_in[1];
  const float* G = (const float*)d_in[2];
  float* out = (float*)d_out;
  char* ws = (char*)d_ws;

  size_t o_xsq  = 0;                                  // 64 KB
  size_t o_wsq  = o_xsq + 65536;                      // 16 KB
  size_t o_xhi  = o_wsq + 16384;                      // 16 MB
  size_t o_whi  = o_xhi + (size_t)B_ * K_ * 2;        // 4 MB
  size_t o_gm   = o_whi + (size_t)H_ * K_ * 2;        // 16 MB
  size_t o_mk   = o_gm + (size_t)B_ * 256 * 4;        // 8 MB
  size_t o_gt   = o_mk + (size_t)B_ * 256 * 2;        // 8 MB
  size_t need   = o_gt + (size_t)H_ * O_ * 4;

  if (ws_size >= need) {
    float* xsq = (float*)(ws + o_xsq);
    float* wsq = (float*)(ws + o_wsq);
    unsigned short* xhi = (unsigned short*)(ws + o_xhi);
    unsigned short* whi = (unsigned short*)(ws + o_whi);
    float* gm = (float*)(ws + o_gm);
    unsigned short* mk = (unsigned short*)(ws + o_mk);
    float* GT = (float*)(ws + o_gt);

    hipLaunchKernelGGL(prep_rows_kernel, dim3(B_ / 8), dim3(256), 0, stream,
                       x, xhi, xsq, B_);
    hipLaunchKernelGGL(prep_rows_kernel, dim3(H_ / 8), dim3(256), 0, stream,
                       W, whi, wsq, H_);
    hipLaunchKernelGGL(transposeG_kernel, dim3(H_ / 32, O_ / 32), dim3(32, 8), 0, stream,
                       G, GT);
    hipLaunchKernelGGL(phase1_mfma_kernel, dim3(B_ / 256, H_ / 256), dim3(512), 0, stream,
                       xhi, whi, wsq, xsq, gm, mk);
    hipLaunchKernelGGL(phase2_wave_kernel, dim3(B_ / 4), dim3(256), 0, stream,
                       gm, mk, x, W, xsq, wsq, GT, out);
    return;
  }

  // Fallback: round-1 exact path
  unsigned long long* keys = (unsigned long long*)ws;
  float* xsq = (float*)(ws + 131072);
  float* wsq = (float*)(ws + 131072 + 65536);
  float* GT = (float*)(ws + 131072 + 65536 + 16384);
  size_t base = 131072 + 65536 + 16384;
  int useGT = ws_size >= base + (size_t)H_ * O_ * 4 ? 1 : 0;

  hipLaunchKernelGGL(init_keys_kernel, dim3(B_ / 256), dim3(256), 0, stream, keys);
  hipLaunchKernelGGL(rowsumsq_kernel, dim3(B_ / 256), dim3(256), 0, stream, x, xsq, B_);
  hipLaunchKernelGGL(rowsumsq_kernel, dim3(H_ / 256), dim3(256), 0, stream, W, wsq, H_);
  if (useGT)
    hipLaunchKernelGGL(transposeG_kernel, dim3(H_ / 32, O_ / 32), dim3(32, 8), 0, stream,
                       G, GT);
  hipLaunchKernelGGL(dist_argmin_kernel, dim3(B_ / BM, H_ / BN), dim3(256), 0, stream,
                     x, W, xsq, wsq, keys);
  hipLaunchKernelGGL(finalize_kernel, dim3(B_), dim3(128), 0, stream, keys, GT, G, out,
                     useGT);
}

// Round 15
// 128.086 us; speedup vs baseline: 1.4060x; 1.4060x over previous
//
#include <hip/hip_runtime.h>
#include <cstdint>
#include <cstddef>

#define B_ 16384
#define K_ 512
#define H_ 4096
#define O_ 512

typedef __attribute__((ext_vector_type(4))) float f32x4;
typedef __attribute__((ext_vector_type(8))) short bf16x8;

#define EPS_FLAG 0.125f

// ---------------------------------------------------------------------------
// Exact helpers (bitwise vs numpy reference — proven in rounds 1-12)
// ---------------------------------------------------------------------------
__device__ inline unsigned short f32_to_bf16_rne(float f) {
  unsigned u = __float_as_uint(f);
  unsigned r = (u + 0x7fffu + ((u >> 16) & 1u)) >> 16;
  return (unsigned short)r;
}

__device__ float np_pairwise_sumsq512(const float* __restrict__ a) {
  float s[4];
  #pragma unroll
  for (int blk = 0; blk < 4; ++blk) {
    const float* p = a + blk * 128;
    float r[8];
    #pragma unroll
    for (int j = 0; j < 8; ++j) r[j] = __fmul_rn(p[j], p[j]);
    for (int i = 8; i < 128; i += 8) {
      #pragma unroll
      for (int j = 0; j < 8; ++j) r[j] = __fadd_rn(r[j], __fmul_rn(p[i + j], p[i + j]));
    }
    s[blk] = __fadd_rn(__fadd_rn(__fadd_rn(r[0], r[1]), __fadd_rn(r[2], r[3])),
                       __fadd_rn(__fadd_rn(r[4], r[5]), __fadd_rn(r[6], r[7])));
  }
  return __fadd_rn(__fadd_rn(s[0], s[1]), __fadd_rn(s[2], s[3]));
}

__global__ __launch_bounds__(256) void prep_rows_kernel(
    const float* __restrict__ src, unsigned short* __restrict__ hi,
    float* __restrict__ sumsq, int nrows) {
  __shared__ float buf[8 * 512];
  const int r0 = blockIdx.x * 8;
  const int tid = (int)threadIdx.x;

  #pragma unroll
  for (int it = 0; it < 4; ++it) {
    int i = tid + it * 256;
    float4 v = ((const float4*)(src + (size_t)r0 * K_))[i];
    ((float4*)buf)[i] = v;
    ushort4 h;
    h.x = f32_to_bf16_rne(v.x);
    h.y = f32_to_bf16_rne(v.y);
    h.z = f32_to_bf16_rne(v.z);
    h.w = f32_to_bf16_rne(v.w);
    ((ushort4*)(hi + (size_t)r0 * K_))[i] = h;
  }
  __syncthreads();

  const int row = tid >> 5, l = tid & 31, blk = l >> 3, j = l & 7;
  const float* p = buf + row * 512 + blk * 128;
  float r = __fmul_rn(p[j], p[j]);
  #pragma unroll
  for (int i = 8; i < 128; i += 8) r = __fadd_rn(r, __fmul_rn(p[i + j], p[i + j]));
  r = __fadd_rn(r, __shfl_xor(r, 1));
  r = __fadd_rn(r, __shfl_xor(r, 2));
  r = __fadd_rn(r, __shfl_xor(r, 4));
  r = __fadd_rn(r, __shfl_xor(r, 8));
  r = __fadd_rn(r, __shfl_xor(r, 16));
  if (l == 0 && r0 + row < nrows) sumsq[r0 + row] = r;
}

__global__ void rowsumsq_kernel(const float* __restrict__ src, float* __restrict__ dst,
                                int nrows) {
  int r = blockIdx.x * blockDim.x + threadIdx.x;
  if (r < nrows) dst[r] = np_pairwise_sumsq512(src + (size_t)r * K_);
}

// G [O_][H_] -> GT [H_][O_]
__global__ void transposeG_kernel(const float* __restrict__ G, float* __restrict__ GT) {
  __shared__ float t[32][33];
  int h0 = blockIdx.x * 32, o0 = blockIdx.y * 32;
  for (int i = threadIdx.y; i < 32; i += 8)
    t[i][threadIdx.x] = G[(size_t)(o0 + i) * H_ + h0 + threadIdx.x];
  __syncthreads();
  for (int i = threadIdx.y; i < 32; i += 8)
    GT[(size_t)(h0 + i) * O_ + o0 + threadIdx.x] = t[threadIdx.x][i];
}

// ---------------------------------------------------------------------------
// Phase 1 (R12-proven, 95.8us): BK=64, XOR-8 swizzle, 2-phase double buffer.
// ---------------------------------------------------------------------------
__device__ inline void stage_tile64(char* lds_base, const unsigned short* __restrict__ src,
                                    int row0, int kt, int wid, int lane) {
  #pragma unroll
  for (int j = 0; j < 4; ++j) {
    int chunk = wid + j * 4;
    int u = chunk * 64 + lane;
    int row = u >> 3, slot = u & 7;
    int slot_src = slot ^ (row & 7);
    const char* g = (const char*)src + (size_t)(row0 + row) * (K_ * 2) + kt * 128 + slot_src * 16;
    char* l = lds_base + chunk * 1024;
    __builtin_amdgcn_global_load_lds((const __attribute__((address_space(1))) void*)g,
                                     (__attribute__((address_space(3))) void*)l,
                                     16, 0, 0);
  }
}

__global__ __launch_bounds__(256) void phase1_mfma_kernel(
    const unsigned short* __restrict__ xhi, const unsigned short* __restrict__ whi,
    const float* __restrict__ wsq, const float* __restrict__ xsq,
    float* __restrict__ gmin16 /*[B_][256]*/,
    unsigned short* __restrict__ mk16 /*[B_][256]*/) {
  __shared__ __align__(16) char smem[65536];
  const int tid = (int)threadIdx.x;
  const int wid = tid >> 6, lane = tid & 63;
  const int wr = wid >> 1, wc = wid & 1;
  const int cb = blockIdx.y;
  const int row0 = blockIdx.x * 128, col0 = cb * 128;

  f32x4 acc[4][4];
  #pragma unroll
  for (int i = 0; i < 4; ++i)
    #pragma unroll
    for (int j = 0; j < 4; ++j) acc[i][j] = (f32x4){0.f, 0.f, 0.f, 0.f};

  const int arow = wr * 64 + (lane & 15);
  const int brow = wc * 64 + (lane & 15);
  const int r7 = lane & 7, sg = lane >> 4;
  const int offK0 = ((sg ^ r7) & 7) * 16;
  const int offK1 = (((4 + sg) ^ r7) & 7) * 16;

  stage_tile64(smem, xhi, row0, 0, wid, lane);
  stage_tile64(smem + 16384, whi, col0, 0, wid, lane);
  __syncthreads();

  int buf = 0;
  for (int kt = 0; kt < 8; ++kt) {
    if (kt < 7) {
      stage_tile64(smem + (buf ^ 1) * 32768, xhi, row0, kt + 1, wid, lane);
      stage_tile64(smem + (buf ^ 1) * 32768 + 16384, whi, col0, kt + 1, wid, lane);
    }
    const char* A = smem + buf * 32768;
    const char* Bm = smem + buf * 32768 + 16384;
    #pragma unroll
    for (int ks = 0; ks < 2; ++ks) {
      const int offK = ks ? offK1 : offK0;
      bf16x8 ah[4];
      #pragma unroll
      for (int mf = 0; mf < 4; ++mf)
        ah[mf] = *(const bf16x8*)(A + (arow + mf * 16) * 128 + offK);
      #pragma unroll
      for (int nf = 0; nf < 4; ++nf) {
        bf16x8 bh = *(const bf16x8*)(Bm + (brow + nf * 16) * 128 + offK);
        #pragma unroll
        for (int mf = 0; mf < 4; ++mf)
          acc[mf][nf] = __builtin_amdgcn_mfma_f32_16x16x32_bf16(ah[mf], bh, acc[mf][nf], 0, 0, 0);
      }
    }
    __syncthreads();
    buf ^= 1;
  }

  // ---- epilogue (R10-proven) ----
  float* T = (float*)smem + wid * (16 * 65);
  float* EpiF = (float*)(smem + 16640);
  unsigned short* EpiM = (unsigned short*)(smem + 21248);

  const float xq = xsq[row0 + wr * 64 + lane];
  const int c = lane & 15;

  #pragma unroll
  for (int nf = 0; nf < 4; ++nf) {
    float wq = wsq[col0 + wc * 64 + nf * 16 + c];
    #pragma unroll
    for (int mf = 0; mf < 4; ++mf)
      #pragma unroll
      for (int r = 0; r < 4; ++r)
        T[c * 65 + (mf * 16 + sg * 4 + r)] = wq - 2.0f * acc[mf][nf][r];
    asm volatile("s_waitcnt lgkmcnt(0)" ::: "memory");
    __builtin_amdgcn_sched_barrier(0);
    float v[16];
    #pragma unroll
    for (int c2 = 0; c2 < 16; ++c2) v[c2] = T[c2 * 65 + lane];
    float mn = v[0];
    #pragma unroll
    for (int c2 = 1; c2 < 16; ++c2) mn = fminf(mn, v[c2]);
    unsigned msk = 0;
    #pragma unroll
    for (int c2 = 0; c2 < 16; ++c2)
      if ((v[c2] <= mn + EPS_FLAG) || (v[c2] + xq <= EPS_FLAG)) msk |= 1u << c2;
    EpiF[(wr * 64 + lane) * 9 + wc * 4 + nf] = mn;
    EpiM[(wr * 64 + lane) * 8 + wc * 4 + nf] = (unsigned short)msk;
  }
  __syncthreads();

  {
    int row = tid >> 1, half = tid & 1;
    float4 vf;
    vf.x = EpiF[row * 9 + half * 4 + 0];
    vf.y = EpiF[row * 9 + half * 4 + 1];
    vf.z = EpiF[row * 9 + half * 4 + 2];
    vf.w = EpiF[row * 9 + half * 4 + 3];
    *(float4*)&gmin16[(size_t)(row0 + row) * 256 + cb * 8 + half * 4] = vf;
    if (tid < 128) {
      uint4 vm = *(const uint4*)&EpiM[tid * 8];
      *(uint4*)&mk16[(size_t)(row0 + tid) * 256 + cb * 8] = vm;
    }
  }
}

// ---------------------------------------------------------------------------
// Phase 2 v2 (fixed ownership): 16 rows/block, grid 1024 (4 blocks/CU).
// Thread t16 owns groups [t16*16, t16*16+16) for BOTH gm and mk — same key,
// same mapping, loaded contiguously (coalesced 64B/32B per thread).
// (a) flag + append (r<<12|col) entries to shared list via LDS atomicAdd
//     (order-irrelevant: final (dist_bits,h) atomicMin is order-independent).
// (b) all 256 threads grid-stride the list; each runs one bitwise-exact
//     ascending-k FMA chain (x from LDS stride-516, W from global).
// (c) 16 thr/row GT gather + index write.
// Generic per-row fallback if list overflows (never in practice).
// ---------------------------------------------------------------------------
#define P2_ROWS 16
#define P2_CAP 2048

__global__ __launch_bounds__(256) void phase2_block_kernel(
    const float* __restrict__ gm /*[B_][256]*/,
    const unsigned short* __restrict__ mk /*[B_][256]*/,
    const float* __restrict__ x, const float* __restrict__ W,
    const float* __restrict__ xsq, const float* __restrict__ wsq,
    const float* __restrict__ GT, float* __restrict__ out) {
  __shared__ float xls[P2_ROWS * 516];                 // 33 KB
  __shared__ unsigned short clist[P2_CAP];             // 4 KB
  __shared__ unsigned long long bestkey[P2_ROWS];
  __shared__ int ncand;
  const int tid = (int)threadIdx.x;
  const int r = tid >> 4, t16 = tid & 15;
  const int b0 = blockIdx.x * P2_ROWS;
  const int b = b0 + r;

  if (tid < P2_ROWS) bestkey[tid] = 0xFFFFFFFFFFFFFFFFULL;
  if (tid == 0) ncand = 0;

  // stage 16 x-rows into LDS (coalesced float4, stride 516 floats)
  #pragma unroll
  for (int it = 0; it < 8; ++it) {
    int idx = tid + it * 256;            // 0..2047 float4s
    int xr = idx >> 7, xw = idx & 127;
    float4 v = ((const float4*)(x + (size_t)(b0 + xr) * K_))[xw];
    *(float4*)&xls[xr * 516 + xw * 4] = v;
  }

  // thread t16 owns groups [t16*16, t16*16+16) for both gm and mk
  float gv[16];
  #pragma unroll
  for (int j = 0; j < 4; ++j) {
    float4 v = *(const float4*)(gm + (size_t)b * 256 + t16 * 16 + j * 4);
    gv[j * 4 + 0] = v.x;
    gv[j * 4 + 1] = v.y;
    gv[j * 4 + 2] = v.z;
    gv[j * 4 + 3] = v.w;
  }
  unsigned short mv[16];
  #pragma unroll
  for (int j = 0; j < 2; ++j) {
    uint4 u = *(const uint4*)(mk + (size_t)b * 256 + t16 * 16 + j * 8);
    mv[j * 8 + 0] = (unsigned short)(u.x & 0xFFFF);
    mv[j * 8 + 1] = (unsigned short)(u.x >> 16);
    mv[j * 8 + 2] = (unsigned short)(u.y & 0xFFFF);
    mv[j * 8 + 3] = (unsigned short)(u.y >> 16);
    mv[j * 8 + 4] = (unsigned short)(u.z & 0xFFFF);
    mv[j * 8 + 5] = (unsigned short)(u.z >> 16);
    mv[j * 8 + 6] = (unsigned short)(u.w & 0xFFFF);
    mv[j * 8 + 7] = (unsigned short)(u.w >> 16);
  }

  float mn = gv[0];
  #pragma unroll
  for (int j = 1; j < 16; ++j) mn = fminf(mn, gv[j]);
  #pragma unroll
  for (int off = 1; off < 16; off <<= 1) mn = fminf(mn, __shfl_xor(mn, off, 16));
  const float xq = xsq[b];
  const float thr = mn + EPS_FLAG;
  __syncthreads();   // xls staged; ncand/bestkey init visible

  // flag + append candidates (gv[j] and mv[j] both refer to group t16*16+j)
  #pragma unroll
  for (int j = 0; j < 16; ++j) {
    float v = gv[j];
    if ((v <= thr) || (v + xq <= EPS_FLAG)) {
      int g = t16 * 16 + j;
      unsigned mbits = mv[j];
      while (mbits) {
        int bit = __ffs(mbits) - 1;
        mbits &= mbits - 1;
        int slot = atomicAdd(&ncand, 1);
        if (slot < P2_CAP)
          clist[slot] = (unsigned short)((r << 12) | (g * 16 + bit));
      }
    }
  }
  __syncthreads();

  int total = ncand;
  if (total <= P2_CAP) {
    for (int i = tid; i < total; i += 256) {
      unsigned e = clist[i];
      int rr = (int)(e >> 12);
      int col = (int)(e & 0xFFF);
      const float* xr = xls + rr * 516;
      const float4* wrow = (const float4*)(W + (size_t)col * K_);
      float acc = 0.0f;
      #pragma unroll 8
      for (int kq = 0; kq < K_ / 4; ++kq) {
        float4 xv = *(const float4*)&xr[kq * 4];
        float4 wv = wrow[kq];
        acc = fmaf(xv.x, wv.x, acc);
        acc = fmaf(xv.y, wv.y, acc);
        acc = fmaf(xv.z, wv.z, acc);
        acc = fmaf(xv.w, wv.w, acc);
      }
      float xqr = xsq[b0 + rr];
      float t2 = xqr - 2.0f * acc;
      float sq = t2 + wsq[col];
      float d = sqrtf(fmaxf(sq, 0.0f));
      unsigned long long key =
          ((unsigned long long)__float_as_uint(d) << 32) | (unsigned)col;
      atomicMin(&bestkey[rr], key);
    }
  } else {
    // generic fallback: 16 threads/row scan all cols (never in practice)
    for (int cc = t16; cc < H_; cc += 16) {
      int g = cc >> 4;
      float gvv = gm[(size_t)b * 256 + g];
      if ((gvv <= thr || gvv + xq <= EPS_FLAG) &&
          ((mk[(size_t)b * 256 + g] >> (cc & 15)) & 1)) {
        const float* xr = xls + r * 516;
        const float4* wrow = (const float4*)(W + (size_t)cc * K_);
        float acc = 0.0f;
        #pragma unroll 8
        for (int kq = 0; kq < K_ / 4; ++kq) {
          float4 xv = *(const float4*)&xr[kq * 4];
          float4 wv = wrow[kq];
          acc = fmaf(xv.x, wv.x, acc);
          acc = fmaf(xv.y, wv.y, acc);
          acc = fmaf(xv.z, wv.z, acc);
          acc = fmaf(xv.w, wv.w, acc);
        }
        float t2 = xq - 2.0f * acc;
        float sq = t2 + wsq[cc];
        float d = sqrtf(fmaxf(sq, 0.0f));
        unsigned long long key =
            ((unsigned long long)__float_as_uint(d) << 32) | (unsigned)cc;
        atomicMin(&bestkey[r], key);
      }
    }
  }
  __syncthreads();

  // gather GT[h] per row + index write (16 threads/row, coalesced)
  {
    const unsigned h = (unsigned)(bestkey[r] & 0xFFFFFFFFULL);
    const float4* gsrc = (const float4*)(GT + (size_t)h * O_);
    float4* gdst = (float4*)(out + (size_t)b * O_);
    #pragma unroll
    for (int j = 0; j < 8; ++j) gdst[j * 16 + t16] = gsrc[j * 16 + t16];
    if (t16 == 0) out[(size_t)B_ * O_ + b] = (float)h;
  }
}

// ---------------------------------------------------------------------------
// Round-1 fallback (exact f32 vector GEMM + argmin) — used only if ws too small
// ---------------------------------------------------------------------------
#define BM 128
#define BN 128
#define BKK 16

__global__ void init_keys_kernel(unsigned long long* __restrict__ keys) {
  int i = blockIdx.x * blockDim.x + threadIdx.x;
  if (i < B_) keys[i] = 0xFFFFFFFFFFFFFFFFULL;
}

__global__ __launch_bounds__(256) void dist_argmin_kernel(
    const float* __restrict__ x, const float* __restrict__ W,
    const float* __restrict__ xsq, const float* __restrict__ wsq,
    unsigned long long* __restrict__ keys) {
  __shared__ float xs[BKK][BM + 4];
  __shared__ float wsh[BKK][BN + 4];
  const int row0 = blockIdx.x * BM;
  const int col0 = blockIdx.y * BN;
  const int tid = (int)threadIdx.x;
  const int tx = tid & 15, ty = tid >> 4;

  float acc[8][8];
  #pragma unroll
  for (int i = 0; i < 8; ++i)
    #pragma unroll
    for (int j = 0; j < 8; ++j) acc[i][j] = 0.0f;

  for (int kt = 0; kt < K_; kt += BKK) {
    #pragma unroll
    for (int l = 0; l < 2; ++l) {
      int e = tid + l * 256;
      int r = e >> 2, kq = e & 3;
      float4 v = *(const float4*)(x + (size_t)(row0 + r) * K_ + kt + kq * 4);
      xs[kq * 4 + 0][r] = v.x;
      xs[kq * 4 + 1][r] = v.y;
      xs[kq * 4 + 2][r] = v.z;
      xs[kq * 4 + 3][r] = v.w;
      float4 u = *(const float4*)(W + (size_t)(col0 + r) * K_ + kt + kq * 4);
      wsh[kq * 4 + 0][r] = u.x;
      wsh[kq * 4 + 1][r] = u.y;
      wsh[kq * 4 + 2][r] = u.z;
      wsh[kq * 4 + 3][r] = u.w;
    }
    __syncthreads();
    #pragma unroll
    for (int k = 0; k < BKK; ++k) {
      float4 a0 = *(const float4*)&xs[k][ty * 4];
      float4 a1 = *(const float4*)&xs[k][ty * 4 + 64];
      float4 b0 = *(const float4*)&wsh[k][tx * 4];
      float4 b1 = *(const float4*)&wsh[k][tx * 4 + 64];
      float ar[8] = {a0.x, a0.y, a0.z, a0.w, a1.x, a1.y, a1.z, a1.w};
      float br[8] = {b0.x, b0.y, b0.z, b0.w, b1.x, b1.y, b1.z, b1.w};
      #pragma unroll
      for (int i = 0; i < 8; ++i)
        #pragma unroll
        for (int j = 0; j < 8; ++j)
          acc[i][j] = fmaf(ar[i], br[j], acc[i][j]);
    }
    __syncthreads();
  }

  float xv[8], wv[8];
  int rowidx[8], colidx[8];
  #pragma unroll
  for (int i = 0; i < 8; ++i) {
    rowidx[i] = row0 + ty * 4 + (i & 3) + (i >> 2) * 64;
    xv[i] = xsq[rowidx[i]];
  }
  #pragma unroll
  for (int j = 0; j < 8; ++j) {
    colidx[j] = col0 + tx * 4 + (j & 3) + (j >> 2) * 64;
    wv[j] = wsq[colidx[j]];
  }
  #pragma unroll
  for (int i = 0; i < 8; ++i) {
    unsigned long long best = 0xFFFFFFFFFFFFFFFFULL;
    #pragma unroll
    for (int j = 0; j < 8; ++j) {
      float t2 = xv[i] - 2.0f * acc[i][j];
      float sq = t2 + wv[j];
      float d = sqrtf(fmaxf(sq, 0.0f));
      unsigned long long key =
          ((unsigned long long)__float_as_uint(d) << 32) | (unsigned)colidx[j];
      best = key < best ? key : best;
    }
    #pragma unroll
    for (int off = 1; off < 16; off <<= 1) {
      unsigned long long o = __shfl_xor(best, off, 16);
      best = o < best ? o : best;
    }
    if (tx == 0) atomicMin(&keys[rowidx[i]], best);
  }
}

__global__ void finalize_kernel(const unsigned long long* __restrict__ keys,
                                const float* __restrict__ GT,
                                const float* __restrict__ G,
                                float* __restrict__ out, int useGT) {
  int b = blockIdx.x;
  unsigned h = (unsigned)(keys[b] & 0xFFFFFFFFULL);
  if (threadIdx.x == 0) out[(size_t)B_ * O_ + b] = (float)h;
  if (useGT) {
    const float4* src = (const float4*)(GT + (size_t)h * O_);
    float4* dst = (float4*)(out + (size_t)b * O_);
    for (int i = threadIdx.x; i < O_ / 4; i += blockDim.x) dst[i] = src[i];
  } else {
    for (int o = threadIdx.x; o < O_; o += blockDim.x)
      out[(size_t)b * O_ + o] = G[(size_t)o * H_ + h];
  }
}

// ---------------------------------------------------------------------------
extern "C" void kernel_launch(void* const* d_in, const int* in_sizes, int n_in,
                              void* d_out, int out_size, void* d_ws, size_t ws_size,
                              hipStream_t stream) {
  const float* x = (const float*)d_in[0];
  const float* W = (const float*)d_in[1];
  const float* G = (const float*)d_in[2];
  float* out = (float*)d_out;
  char* ws = (char*)d_ws;

  size_t o_xsq  = 0;                                  // 64 KB
  size_t o_wsq  = o_xsq + 65536;                      // 16 KB
  size_t o_xhi  = o_wsq + 16384;                      // 16 MB
  size_t o_whi  = o_xhi + (size_t)B_ * K_ * 2;        // 4 MB
  size_t o_gm   = o_whi + (size_t)H_ * K_ * 2;        // 16 MB
  size_t o_mk   = o_gm + (size_t)B_ * 256 * 4;        // 8 MB
  size_t o_gt   = o_mk + (size_t)B_ * 256 * 2;        // 8 MB
  size_t need   = o_gt + (size_t)H_ * O_ * 4;

  if (ws_size >= need) {
    float* xsq = (float*)(ws + o_xsq);
    float* wsq = (float*)(ws + o_wsq);
    unsigned short* xhi = (unsigned short*)(ws + o_xhi);
    unsigned short* whi = (unsigned short*)(ws + o_whi);
    float* gm = (float*)(ws + o_gm);
    unsigned short* mk = (unsigned short*)(ws + o_mk);
    float* GT = (float*)(ws + o_gt);

    hipLaunchKernelGGL(prep_rows_kernel, dim3(B_ / 8), dim3(256), 0, stream,
                       x, xhi, xsq, B_);
    hipLaunchKernelGGL(prep_rows_kernel, dim3(H_ / 8), dim3(256), 0, stream,
                       W, whi, wsq, H_);
    hipLaunchKernelGGL(transposeG_kernel, dim3(H_ / 32, O_ / 32), dim3(32, 8), 0, stream,
                       G, GT);
    hipLaunchKernelGGL(phase1_mfma_kernel, dim3(B_ / 128, H_ / 128), dim3(256), 0, stream,
                       xhi, whi, wsq, xsq, gm, mk);
    hipLaunchKernelGGL(phase2_block_kernel, dim3(B_ / P2_ROWS), dim3(256), 0, stream,
                       gm, mk, x, W, xsq, wsq, GT, out);
    return;
  }

  // Fallback: round-1 exact path
  unsigned long long* keys = (unsigned long long*)ws;
  float* xsq = (float*)(ws + 131072);
  float* wsq = (float*)(ws + 131072 + 65536);
  float* GT = (float*)(ws + 131072 + 65536 + 16384);
  size_t base = 131072 + 65536 + 16384;
  int useGT = ws_size >= base + (size_t)H_ * O_ * 4 ? 1 : 0;

  hipLaunchKernelGGL(init_keys_kernel, dim3(B_ / 256), dim3(256), 0, stream, keys);
  hipLaunchKernelGGL(rowsumsq_kernel, dim3(B_ / 256), dim3(256), 0, stream, x, xsq, B_);
  hipLaunchKernelGGL(rowsumsq_kernel, dim3(H_ / 256), dim3(256), 0, stream, W, wsq, H_);
  if (useGT)
    hipLaunchKernelGGL(transposeG_kernel, dim3(H_ / 32, O_ / 32), dim3(32, 8), 0, stream,
                       G, GT);
  hipLaunchKernelGGL(dist_argmin_kernel, dim3(B_ / BM, H_ / BN), dim3(256), 0, stream,
                     x, W, xsq, wsq, keys);
  hipLaunchKernelGGL(finalize_kernel, dim3(B_), dim3(128), 0, stream, keys, GT, G, out,
                     useGT);
}

// Round 16
// 119.527 us; speedup vs baseline: 1.5066x; 1.0716x over previous
//
#include <hip/hip_runtime.h>
#include <cstdint>
#include <cstddef>

#define B_ 16384
#define K_ 512
#define H_ 4096
#define O_ 512

typedef __attribute__((ext_vector_type(4))) float f32x4;
typedef __attribute__((ext_vector_type(8))) short bf16x8;

#define EPS_FLAG 0.125f

// ---------------------------------------------------------------------------
// Exact helpers (bitwise vs numpy reference — proven in rounds 1-15)
// ---------------------------------------------------------------------------
__device__ inline unsigned short f32_to_bf16_rne(float f) {
  unsigned u = __float_as_uint(f);
  unsigned r = (u + 0x7fffu + ((u >> 16) & 1u)) >> 16;
  return (unsigned short)r;
}

__device__ float np_pairwise_sumsq512(const float* __restrict__ a) {
  float s[4];
  #pragma unroll
  for (int blk = 0; blk < 4; ++blk) {
    const float* p = a + blk * 128;
    float r[8];
    #pragma unroll
    for (int j = 0; j < 8; ++j) r[j] = __fmul_rn(p[j], p[j]);
    for (int i = 8; i < 128; i += 8) {
      #pragma unroll
      for (int j = 0; j < 8; ++j) r[j] = __fadd_rn(r[j], __fmul_rn(p[i + j], p[i + j]));
    }
    s[blk] = __fadd_rn(__fadd_rn(__fadd_rn(r[0], r[1]), __fadd_rn(r[2], r[3])),
                       __fadd_rn(__fadd_rn(r[4], r[5]), __fadd_rn(r[6], r[7])));
  }
  return __fadd_rn(__fadd_rn(s[0], s[1]), __fadd_rn(s[2], s[3]));
}

// Fused prep: blocks [0,2048) prep x rows; [2048,2560) prep W rows;
// [2560,4608) transpose G. All sub-kernels proven in rounds 3-15.
__global__ __launch_bounds__(256) void prep_all_kernel(
    const float* __restrict__ x, const float* __restrict__ W,
    const float* __restrict__ G,
    unsigned short* __restrict__ xhi, unsigned short* __restrict__ whi,
    float* __restrict__ xsq, float* __restrict__ wsq, float* __restrict__ GT) {
  const int bid = (int)blockIdx.x;
  const int tid = (int)threadIdx.x;

  if (bid < 2560) {
    // prep_rows on x (bid<2048) or W (bid>=2048)
    const float* src = bid < 2048 ? x : W;
    unsigned short* hi = bid < 2048 ? xhi : whi;
    float* sumsq = bid < 2048 ? xsq : wsq;
    const int r0 = (bid < 2048 ? bid : bid - 2048) * 8;

    __shared__ float buf[8 * 512];
    #pragma unroll
    for (int it = 0; it < 4; ++it) {
      int i = tid + it * 256;
      float4 v = ((const float4*)(src + (size_t)r0 * K_))[i];
      ((float4*)buf)[i] = v;
      ushort4 h;
      h.x = f32_to_bf16_rne(v.x);
      h.y = f32_to_bf16_rne(v.y);
      h.z = f32_to_bf16_rne(v.z);
      h.w = f32_to_bf16_rne(v.w);
      ((ushort4*)(hi + (size_t)r0 * K_))[i] = h;
    }
    __syncthreads();

    const int row = tid >> 5, l = tid & 31, blk = l >> 3, j = l & 7;
    const float* p = buf + row * 512 + blk * 128;
    float r = __fmul_rn(p[j], p[j]);
    #pragma unroll
    for (int i = 8; i < 128; i += 8) r = __fadd_rn(r, __fmul_rn(p[i + j], p[i + j]));
    r = __fadd_rn(r, __shfl_xor(r, 1));
    r = __fadd_rn(r, __shfl_xor(r, 2));
    r = __fadd_rn(r, __shfl_xor(r, 4));
    r = __fadd_rn(r, __shfl_xor(r, 8));
    r = __fadd_rn(r, __shfl_xor(r, 16));
    if (l == 0) sumsq[r0 + row] = r;
  } else {
    // transposeG: G [O_][H_] -> GT [H_][O_]
    __shared__ float t[32][33];
    const int bid2 = bid - 2560;
    const int h0 = (bid2 & 127) * 32, o0 = (bid2 >> 7) * 32;
    const int tx = tid & 31, ty = tid >> 5;
    for (int i = ty; i < 32; i += 8)
      t[i][tx] = G[(size_t)(o0 + i) * H_ + h0 + tx];
    __syncthreads();
    for (int i = ty; i < 32; i += 8)
      GT[(size_t)(h0 + i) * O_ + o0 + tx] = t[tx][i];
  }
}

__global__ void rowsumsq_kernel(const float* __restrict__ src, float* __restrict__ dst,
                                int nrows) {
  int r = blockIdx.x * blockDim.x + threadIdx.x;
  if (r < nrows) dst[r] = np_pairwise_sumsq512(src + (size_t)r * K_);
}

__global__ void transposeG_kernel(const float* __restrict__ G, float* __restrict__ GT) {
  __shared__ float t[32][33];
  int h0 = blockIdx.x * 32, o0 = blockIdx.y * 32;
  for (int i = threadIdx.y; i < 32; i += 8)
    t[i][threadIdx.x] = G[(size_t)(o0 + i) * H_ + h0 + threadIdx.x];
  __syncthreads();
  for (int i = threadIdx.y; i < 32; i += 8)
    GT[(size_t)(h0 + i) * O_ + o0 + threadIdx.x] = t[threadIdx.x][i];
}

// ---------------------------------------------------------------------------
// Phase 1: 256x256 tile, 8 waves (2Mx4N, per-wave 128x64 output), BK=64,
// XOR-8 swizzle (R12-proven conflict-free), PLAIN 2-phase double buffer
// (R7-proven sync). Rationale: phase1 is LDS-read-pipe-bound at ~128 B/cyc;
// 128x64 per-wave tile cuts LDS bytes/MFMA 512->384 (A-frags reused 4x).
// Accumulation order per acc entry unchanged (kt,ks ascending) -> bitwise
// identical. Epilogue = R13's (verified absmax 0).
// ---------------------------------------------------------------------------
__device__ inline void stage_panel256(char* lds_panel, const unsigned short* __restrict__ src,
                                      int rowbase, int kt, int tid) {
  // [256][64]bf16 panel = 32KB = 2048 16B-units; 512 threads x 4 units
  #pragma unroll
  for (int j = 0; j < 4; ++j) {
    int u = j * 512 + tid;
    int row = u >> 3, slot = u & 7;
    const char* g = (const char*)src + (size_t)(rowbase + row) * (K_ * 2) + kt * 128 +
                    ((slot ^ (row & 7)) * 16);
    __builtin_amdgcn_global_load_lds((const __attribute__((address_space(1))) void*)g,
                                     (__attribute__((address_space(3))) void*)(lds_panel + u * 16),
                                     16, 0, 0);
  }
}

__global__ __launch_bounds__(512, 2) void phase1_mfma_kernel(
    const unsigned short* __restrict__ xhi, const unsigned short* __restrict__ whi,
    const float* __restrict__ wsq, const float* __restrict__ xsq,
    float* __restrict__ gmin16 /*[B_][256]*/,
    unsigned short* __restrict__ mk16 /*[B_][256]*/) {
  // K-loop: 2 buffers x (A 32KB + B 32KB) = 128KB
  // epilogue union: T 8 x [16][129] f32 (66048B); EpiF [256][16] f32 @66048;
  //                 EpiM [256][16] u16 @82432
  __shared__ __align__(16) char smem[131072];
  const int tid = (int)threadIdx.x;
  const int wid = tid >> 6, lane = tid & 63;
  const int wr = wid >> 2, wc = wid & 3;       // per-wave 128 rows x 64 cols
  const int cb = blockIdx.y;
  const int row0 = blockIdx.x * 256, col0 = cb * 256;

  f32x4 acc[8][4];
  #pragma unroll
  for (int i = 0; i < 8; ++i)
    #pragma unroll
    for (int j = 0; j < 4; ++j) acc[i][j] = (f32x4){0.f, 0.f, 0.f, 0.f};

  const int r16 = lane & 15, r7 = lane & 7, sg = lane >> 4;
  const int offK0 = ((sg ^ r7) & 7) * 16;
  const int offK1 = (((4 + sg) ^ r7) & 7) * 16;
  const int arowb = wr * 128 + r16;            // A base row (local)
  const int browb = wc * 64 + r16;             // B base row (local)

  // prologue: stage kt=0 into buf0
  stage_panel256(smem, xhi, row0, 0, tid);
  stage_panel256(smem + 32768, whi, col0, 0, tid);
  __syncthreads();

  int buf = 0;
  for (int kt = 0; kt < 8; ++kt) {
    if (kt < 7) {
      stage_panel256(smem + (buf ^ 1) * 65536, xhi, row0, kt + 1, tid);
      stage_panel256(smem + (buf ^ 1) * 65536 + 32768, whi, col0, kt + 1, tid);
    }
    const char* A = smem + buf * 65536;
    const char* Bm = smem + buf * 65536 + 32768;
    #pragma unroll
    for (int ks = 0; ks < 2; ++ks) {
      const int offK = ks ? offK1 : offK0;
      bf16x8 ah[8];
      #pragma unroll
      for (int mf = 0; mf < 8; ++mf)
        ah[mf] = *(const bf16x8*)(A + (arowb + mf * 16) * 128 + offK);
      #pragma unroll
      for (int nf = 0; nf < 4; ++nf) {
        bf16x8 bh = *(const bf16x8*)(Bm + (browb + nf * 16) * 128 + offK);
        #pragma unroll
        for (int mf = 0; mf < 8; ++mf)
          acc[mf][nf] = __builtin_amdgcn_mfma_f32_16x16x32_bf16(ah[mf], bh, acc[mf][nf], 0, 0, 0);
      }
    }
    __syncthreads();   // drains next stage + protects buffer reuse (R7-safe)
    buf ^= 1;
  }

  // ---- epilogue (R13-verified) ----
  // D layout: col=lane&15, row=(lane>>4)*4+reg. Per wave: 128 rows x 64 cols.
  float* T = (float*)smem + wid * (16 * 129);                  // [16][129]
  float* EpiF = (float*)(smem + 66048);                        // [256][16]
  unsigned short* EpiM = (unsigned short*)(smem + 82432);      // [256][16]

  const float xq0 = xsq[row0 + wr * 128 + lane];
  const float xq1 = xsq[row0 + wr * 128 + 64 + lane];
  const int c = r16;

  #pragma unroll
  for (int nf = 0; nf < 4; ++nf) {
    float wq = wsq[col0 + wc * 64 + nf * 16 + c];
    #pragma unroll
    for (int mf = 0; mf < 8; ++mf)
      #pragma unroll
      for (int r = 0; r < 4; ++r)
        T[c * 129 + mf * 16 + sg * 4 + r] = wq - 2.0f * acc[mf][nf][r];
    asm volatile("s_waitcnt lgkmcnt(0)" ::: "memory");
    __builtin_amdgcn_sched_barrier(0);
    // lane owns local rows {lane, lane+64}
    #pragma unroll
    for (int half = 0; half < 2; ++half) {
      int lrow = lane + half * 64;
      float xq = half ? xq1 : xq0;
      float v[16];
      #pragma unroll
      for (int c2 = 0; c2 < 16; ++c2) v[c2] = T[c2 * 129 + lrow];
      float mn = v[0];
      #pragma unroll
      for (int c2 = 1; c2 < 16; ++c2) mn = fminf(mn, v[c2]);
      unsigned msk = 0;
      #pragma unroll
      for (int c2 = 0; c2 < 16; ++c2)
        if ((v[c2] <= mn + EPS_FLAG) || (v[c2] + xq <= EPS_FLAG)) msk |= 1u << c2;
      EpiF[(wr * 128 + lrow) * 16 + wc * 4 + nf] = mn;
      EpiM[(wr * 128 + lrow) * 16 + wc * 4 + nf] = (unsigned short)msk;
    }
  }
  __syncthreads();

  // cooperative coalesced store: 256 rows x (16 f32 + 16 u16)
  {
    int row = tid >> 1, hf = tid & 1;
    const float* fr = EpiF + row * 16 + hf * 8;
    size_t gbase = (size_t)(row0 + row) * 256 + cb * 16 + hf * 8;
    *(float4*)&gmin16[gbase] = *(const float4*)fr;
    *(float4*)&gmin16[gbase + 4] = *(const float4*)(fr + 4);
    uint4 mv = *(const uint4*)(EpiM + row * 16 + hf * 8);
    *(uint4*)&mk16[gbase] = mv;
  }
}

// ---------------------------------------------------------------------------
// Phase 2 (R15-proven): 16 rows/block, block-wide candidate compaction.
// ---------------------------------------------------------------------------
#define P2_ROWS 16
#define P2_CAP 2048

__global__ __launch_bounds__(256) void phase2_block_kernel(
    const float* __restrict__ gm /*[B_][256]*/,
    const unsigned short* __restrict__ mk /*[B_][256]*/,
    const float* __restrict__ x, const float* __restrict__ W,
    const float* __restrict__ xsq, const float* __restrict__ wsq,
    const float* __restrict__ GT, float* __restrict__ out) {
  __shared__ float xls[P2_ROWS * 516];
  __shared__ unsigned short clist[P2_CAP];
  __shared__ unsigned long long bestkey[P2_ROWS];
  __shared__ int ncand;
  const int tid = (int)threadIdx.x;
  const int r = tid >> 4, t16 = tid & 15;
  const int b0 = blockIdx.x * P2_ROWS;
  const int b = b0 + r;

  if (tid < P2_ROWS) bestkey[tid] = 0xFFFFFFFFFFFFFFFFULL;
  if (tid == 0) ncand = 0;

  #pragma unroll
  for (int it = 0; it < 8; ++it) {
    int idx = tid + it * 256;
    int xr = idx >> 7, xw = idx & 127;
    float4 v = ((const float4*)(x + (size_t)(b0 + xr) * K_))[xw];
    *(float4*)&xls[xr * 516 + xw * 4] = v;
  }

  // thread t16 owns groups [t16*16, t16*16+16) for both gm and mk
  float gv[16];
  #pragma unroll
  for (int j = 0; j < 4; ++j) {
    float4 v = *(const float4*)(gm + (size_t)b * 256 + t16 * 16 + j * 4);
    gv[j * 4 + 0] = v.x;
    gv[j * 4 + 1] = v.y;
    gv[j * 4 + 2] = v.z;
    gv[j * 4 + 3] = v.w;
  }
  unsigned short mv[16];
  #pragma unroll
  for (int j = 0; j < 2; ++j) {
    uint4 u = *(const uint4*)(mk + (size_t)b * 256 + t16 * 16 + j * 8);
    mv[j * 8 + 0] = (unsigned short)(u.x & 0xFFFF);
    mv[j * 8 + 1] = (unsigned short)(u.x >> 16);
    mv[j * 8 + 2] = (unsigned short)(u.y & 0xFFFF);
    mv[j * 8 + 3] = (unsigned short)(u.y >> 16);
    mv[j * 8 + 4] = (unsigned short)(u.z & 0xFFFF);
    mv[j * 8 + 5] = (unsigned short)(u.z >> 16);
    mv[j * 8 + 6] = (unsigned short)(u.w & 0xFFFF);
    mv[j * 8 + 7] = (unsigned short)(u.w >> 16);
  }

  float mn = gv[0];
  #pragma unroll
  for (int j = 1; j < 16; ++j) mn = fminf(mn, gv[j]);
  #pragma unroll
  for (int off = 1; off < 16; off <<= 1) mn = fminf(mn, __shfl_xor(mn, off, 16));
  const float xq = xsq[b];
  const float thr = mn + EPS_FLAG;
  __syncthreads();

  #pragma unroll
  for (int j = 0; j < 16; ++j) {
    float v = gv[j];
    if ((v <= thr) || (v + xq <= EPS_FLAG)) {
      int g = t16 * 16 + j;
      unsigned mbits = mv[j];
      while (mbits) {
        int bit = __ffs(mbits) - 1;
        mbits &= mbits - 1;
        int slot = atomicAdd(&ncand, 1);
        if (slot < P2_CAP)
          clist[slot] = (unsigned short)((r << 12) | (g * 16 + bit));
      }
    }
  }
  __syncthreads();

  int total = ncand;
  if (total <= P2_CAP) {
    for (int i = tid; i < total; i += 256) {
      unsigned e = clist[i];
      int rr = (int)(e >> 12);
      int col = (int)(e & 0xFFF);
      const float* xr = xls + rr * 516;
      const float4* wrow = (const float4*)(W + (size_t)col * K_);
      float acc = 0.0f;
      #pragma unroll 8
      for (int kq = 0; kq < K_ / 4; ++kq) {
        float4 xv = *(const float4*)&xr[kq * 4];
        float4 wv = wrow[kq];
        acc = fmaf(xv.x, wv.x, acc);
        acc = fmaf(xv.y, wv.y, acc);
        acc = fmaf(xv.z, wv.z, acc);
        acc = fmaf(xv.w, wv.w, acc);
      }
      float xqr = xsq[b0 + rr];
      float t2 = xqr - 2.0f * acc;
      float sq = t2 + wsq[col];
      float d = sqrtf(fmaxf(sq, 0.0f));
      unsigned long long key =
          ((unsigned long long)__float_as_uint(d) << 32) | (unsigned)col;
      atomicMin(&bestkey[rr], key);
    }
  } else {
    for (int cc = t16; cc < H_; cc += 16) {
      int g = cc >> 4;
      float gvv = gm[(size_t)b * 256 + g];
      if ((gvv <= thr || gvv + xq <= EPS_FLAG) &&
          ((mk[(size_t)b * 256 + g] >> (cc & 15)) & 1)) {
        const float* xr = xls + r * 516;
        const float4* wrow = (const float4*)(W + (size_t)cc * K_);
        float acc = 0.0f;
        #pragma unroll 8
        for (int kq = 0; kq < K_ / 4; ++kq) {
          float4 xv = *(const float4*)&xr[kq * 4];
          float4 wv = wrow[kq];
          acc = fmaf(xv.x, wv.x, acc);
          acc = fmaf(xv.y, wv.y, acc);
          acc = fmaf(xv.z, wv.z, acc);
          acc = fmaf(xv.w, wv.w, acc);
        }
        float t2 = xq - 2.0f * acc;
        float sq = t2 + wsq[cc];
        float d = sqrtf(fmaxf(sq, 0.0f));
        unsigned long long key =
            ((unsigned long long)__float_as_uint(d) << 32) | (unsigned)cc;
        atomicMin(&bestkey[r], key);
      }
    }
  }
  __syncthreads();

  {
    const unsigned h = (unsigned)(bestkey[r] & 0xFFFFFFFFULL);
    const float4* gsrc = (const float4*)(GT + (size_t)h * O_);
    float4* gdst = (float4*)(out + (size_t)b * O_);
    #pragma unroll
    for (int j = 0; j < 8; ++j) gdst[j * 16 + t16] = gsrc[j * 16 + t16];
    if (t16 == 0) out[(size_t)B_ * O_ + b] = (float)h;
  }
}

// ---------------------------------------------------------------------------
// Round-1 fallback (exact f32 vector GEMM + argmin) — used only if ws too small
// ---------------------------------------------------------------------------
#define BM 128
#define BN 128
#define BKK 16

__global__ void init_keys_kernel(unsigned long long* __restrict__ keys) {
  int i = blockIdx.x * blockDim.x + threadIdx.x;
  if (i < B_) keys[i] = 0xFFFFFFFFFFFFFFFFULL;
}

__global__ __launch_bounds__(256) void dist_argmin_kernel(
    const float* __restrict__ x, const float* __restrict__ W,
    const float* __restrict__ xsq, const float* __restrict__ wsq,
    unsigned long long* __restrict__ keys) {
  __shared__ float xs[BKK][BM + 4];
  __shared__ float wsh[BKK][BN + 4];
  const int row0 = blockIdx.x * BM;
  const int col0 = blockIdx.y * BN;
  const int tid = (int)threadIdx.x;
  const int tx = tid & 15, ty = tid >> 4;

  float acc[8][8];
  #pragma unroll
  for (int i = 0; i < 8; ++i)
    #pragma unroll
    for (int j = 0; j < 8; ++j) acc[i][j] = 0.0f;

  for (int kt = 0; kt < K_; kt += BKK) {
    #pragma unroll
    for (int l = 0; l < 2; ++l) {
      int e = tid + l * 256;
      int r = e >> 2, kq = e & 3;
      float4 v = *(const float4*)(x + (size_t)(row0 + r) * K_ + kt + kq * 4);
      xs[kq * 4 + 0][r] = v.x;
      xs[kq * 4 + 1][r] = v.y;
      xs[kq * 4 + 2][r] = v.z;
      xs[kq * 4 + 3][r] = v.w;
      float4 u = *(const float4*)(W + (size_t)(col0 + r) * K_ + kt + kq * 4);
      wsh[kq * 4 + 0][r] = u.x;
      wsh[kq * 4 + 1][r] = u.y;
      wsh[kq * 4 + 2][r] = u.z;
      wsh[kq * 4 + 3][r] = u.w;
    }
    __syncthreads();
    #pragma unroll
    for (int k = 0; k < BKK; ++k) {
      float4 a0 = *(const float4*)&xs[k][ty * 4];
      float4 a1 = *(const float4*)&xs[k][ty * 4 + 64];
      float4 b0 = *(const float4*)&wsh[k][tx * 4];
      float4 b1 = *(const float4*)&wsh[k][tx * 4 + 64];
      float ar[8] = {a0.x, a0.y, a0.z, a0.w, a1.x, a1.y, a1.z, a1.w};
      float br[8] = {b0.x, b0.y, b0.z, b0.w, b1.x, b1.y, b1.z, b1.w};
      #pragma unroll
      for (int i = 0; i < 8; ++i)
        #pragma unroll
        for (int j = 0; j < 8; ++j)
          acc[i][j] = fmaf(ar[i], br[j], acc[i][j]);
    }
    __syncthreads();
  }

  float xv[8], wv[8];
  int rowidx[8], colidx[8];
  #pragma unroll
  for (int i = 0; i < 8; ++i) {
    rowidx[i] = row0 + ty * 4 + (i & 3) + (i >> 2) * 64;
    xv[i] = xsq[rowidx[i]];
  }
  #pragma unroll
  for (int j = 0; j < 8; ++j) {
    colidx[j] = col0 + tx * 4 + (j & 3) + (j >> 2) * 64;
    wv[j] = wsq[colidx[j]];
  }
  #pragma unroll
  for (int i = 0; i < 8; ++i) {
    unsigned long long best = 0xFFFFFFFFFFFFFFFFULL;
    #pragma unroll
    for (int j = 0; j < 8; ++j) {
      float t2 = xv[i] - 2.0f * acc[i][j];
      float sq = t2 + wv[j];
      float d = sqrtf(fmaxf(sq, 0.0f));
      unsigned long long key =
          ((unsigned long long)__float_as_uint(d) << 32) | (unsigned)colidx[j];
      best = key < best ? key : best;
    }
    #pragma unroll
    for (int off = 1; off < 16; off <<= 1) {
      unsigned long long o = __shfl_xor(best, off, 16);
      best = o < best ? o : best;
    }
    if (tx == 0) atomicMin(&keys[rowidx[i]], best);
  }
}

__global__ void finalize_kernel(const unsigned long long* __restrict__ keys,
                                const float* __restrict__ GT,
                                const float* __restrict__ G,
                                float* __restrict__ out, int useGT) {
  int b = blockIdx.x;
  unsigned h = (unsigned)(keys[b] & 0xFFFFFFFFULL);
  if (threadIdx.x == 0) out[(size_t)B_ * O_ + b] = (float)h;
  if (useGT) {
    const float4* src = (const float4*)(GT + (size_t)h * O_);
    float4* dst = (float4*)(out + (size_t)b * O_);
    for (int i = threadIdx.x; i < O_ / 4; i += blockDim.x) dst[i] = src[i];
  } else {
    for (int o = threadIdx.x; o < O_; o += blockDim.x)
      out[(size_t)b * O_ + o] = G[(size_t)o * H_ + h];
  }
}

// ---------------------------------------------------------------------------
extern "C" void kernel_launch(void* const* d_in, const int* in_sizes, int n_in,
                              void* d_out, int out_size, void* d_ws, size_t ws_size,
                              hipStream_t stream) {
  const float* x = (const float*)d_in[0];
  const float* W = (const float*)d_in[1];
  const float* G = (const float*)d_in[2];
  float* out = (float*)d_out;
  char* ws = (char*)d_ws;

  size_t o_xsq  = 0;                                  // 64 KB
  size_t o_wsq  = o_xsq + 65536;                      // 16 KB
  size_t o_xhi  = o_wsq + 16384;                      // 16 MB
  size_t o_whi  = o_xhi + (size_t)B_ * K_ * 2;        // 4 MB
  size_t o_gm   = o_whi + (size_t)H_ * K_ * 2;        // 16 MB
  size_t o_mk   = o_gm + (size_t)B_ * 256 * 4;        // 8 MB
  size_t o_gt   = o_mk + (size_t)B_ * 256 * 2;        // 8 MB
  size_t need   = o_gt + (size_t)H_ * O_ * 4;

  if (ws_size >= need) {
    float* xsq = (float*)(ws + o_xsq);
    float* wsq = (float*)(ws + o_wsq);
    unsigned short* xhi = (unsigned short*)(ws + o_xhi);
    unsigned short* whi = (unsigned short*)(ws + o_whi);
    float* gm = (float*)(ws + o_gm);
    unsigned short* mk = (unsigned short*)(ws + o_mk);
    float* GT = (float*)(ws + o_gt);

    hipLaunchKernelGGL(prep_all_kernel, dim3(2048 + 512 + 2048), dim3(256), 0, stream,
                       x, W, G, xhi, whi, xsq, wsq, GT);
    hipLaunchKernelGGL(phase1_mfma_kernel, dim3(B_ / 256, H_ / 256), dim3(512), 0, stream,
                       xhi, whi, wsq, xsq, gm, mk);
    hipLaunchKernelGGL(phase2_block_kernel, dim3(B_ / P2_ROWS), dim3(256), 0, stream,
                       gm, mk, x, W, xsq, wsq, GT, out);
    return;
  }

  // Fallback: round-1 exact path
  unsigned long long* keys = (unsigned long long*)ws;
  float* xsq = (float*)(ws + 131072);
  float* wsq = (float*)(ws + 131072 + 65536);
  float* GT = (float*)(ws + 131072 + 65536 + 16384);
  size_t base = 131072 + 65536 + 16384;
  int useGT = ws_size >= base + (size_t)H_ * O_ * 4 ? 1 : 0;

  hipLaunchKernelGGL(init_keys_kernel, dim3(B_ / 256), dim3(256), 0, stream, keys);
  hipLaunchKernelGGL(rowsumsq_kernel, dim3(B_ / 256), dim3(256), 0, stream, x, xsq, B_);
  hipLaunchKernelGGL(rowsumsq_kernel, dim3(H_ / 256), dim3(256), 0, stream, W, wsq, H_);
  if (useGT)
    hipLaunchKernelGGL(transposeG_kernel, dim3(H_ / 32, O_ / 32), dim3(32, 8), 0, stream,
                       G, GT);
  hipLaunchKernelGGL(dist_argmin_kernel, dim3(B_ / BM, H_ / BN), dim3(256), 0, stream,
                     x, W, xsq, wsq, keys);
  hipLaunchKernelGGL(finalize_kernel, dim3(B_), dim3(128), 0, stream, keys, GT, G, out,
                     useGT);
}